// Round 1
// baseline (2005.685 us; speedup 1.0000x reference)
//
#include <hip/hip_runtime.h>
#include <hip/hip_bf16.h>
#include <stdint.h>

typedef float  f32x4 __attribute__((ext_vector_type(4)));
typedef __bf16 bf16x8 __attribute__((ext_vector_type(8)));
typedef unsigned short u16x8 __attribute__((ext_vector_type(8)));

#define BM 128
#define BN 128
#define BK 32

__device__ __forceinline__ unsigned short f2bf_rne(float f) {
    uint32_t x = __float_as_uint(f);
    uint32_t r = x + 0x7FFFu + ((x >> 16) & 1u);
    return (unsigned short)(r >> 16);
}

// fp32 -> bf16 conversion, 8 elems/thread/iter, vectorized 16B loads + 16B stores
__global__ __launch_bounds__(256) void cvt_f32_bf16(const float* __restrict__ src,
                                                    unsigned short* __restrict__ dst,
                                                    long n) {
    long i0 = ((long)blockIdx.x * blockDim.x + threadIdx.x) * 8;
    long stride = (long)gridDim.x * blockDim.x * 8;
    for (long j = i0; j + 8 <= n; j += stride) {
        float4 v0 = *(const float4*)(src + j);
        float4 v1 = *(const float4*)(src + j + 4);
        u16x8 o;
        o[0] = f2bf_rne(v0.x); o[1] = f2bf_rne(v0.y);
        o[2] = f2bf_rne(v0.z); o[3] = f2bf_rne(v0.w);
        o[4] = f2bf_rne(v1.x); o[5] = f2bf_rne(v1.y);
        o[6] = f2bf_rne(v1.z); o[7] = f2bf_rne(v1.w);
        *(u16x8*)(dst + j) = o;
    }
}

// m97-structure bf16 GEMM, B^T layout (W is [N][K] row-major), bias fused.
// 128x128 tile, 4 waves (2x2), each wave 64x64 = 4x4 fragments of 16x16x32 MFMA.
__global__ __launch_bounds__(256) void gemm_bt_bias(const unsigned short* __restrict__ A,
                                                    const unsigned short* __restrict__ B,
                                                    const float* __restrict__ bias,
                                                    float* __restrict__ C,
                                                    int M, int N, int K) {
    __shared__ unsigned short lds_a[BM * BK];  // 8 KiB
    __shared__ unsigned short lds_b[BN * BK];  // 8 KiB

    const int tid  = threadIdx.x;
    const int lane = tid & 63;
    const int wave = tid >> 6;
    const int wr = wave >> 1;   // wave row 0..1
    const int wc = wave & 1;    // wave col 0..1
    const int l15 = lane & 15;
    const int l4  = lane >> 4;  // 0..3

    const int nTilesN = N / BN;
    const int tm = blockIdx.x / nTilesN;
    const int tn = blockIdx.x % nTilesN;
    const long m0 = (long)tm * BM;
    const long n0 = (long)tn * BN;

    f32x4 acc[4][4] = {};

    // staging: thread covers bytes tid*16 + i*4096 of the 8 KiB tile (i = 0,1)
    // elem e = tid*8 + i*2048 ; row = e/32 = tid/4 + i*64 ; col = e%32 = (tid&3)*8
    const unsigned short* aSrc = A + (m0 + (tid >> 2)) * (long)K + ((tid & 3) * 8);
    const unsigned short* bSrc = B + (n0 + (tid >> 2)) * (long)K + ((tid & 3) * 8);
    char* aDst = (char*)lds_a + tid * 16;
    char* bDst = (char*)lds_b + tid * 16;

    for (int k0 = 0; k0 < K; k0 += BK) {
#pragma unroll
        for (int i = 0; i < 2; i++) {
            __builtin_amdgcn_global_load_lds(
                (const __attribute__((address_space(1))) void*)(aSrc + (long)i * 64 * K + k0),
                (__attribute__((address_space(3))) void*)(aDst + i * 4096), 16, 0, 0);
            __builtin_amdgcn_global_load_lds(
                (const __attribute__((address_space(1))) void*)(bSrc + (long)i * 64 * K + k0),
                (__attribute__((address_space(3))) void*)(bDst + i * 4096), 16, 0, 0);
        }
        __syncthreads();  // compiler drains vmcnt before s_barrier

        bf16x8 af[4], bfr[4];
#pragma unroll
        for (int r = 0; r < 4; r++)
            af[r] = *(const bf16x8*)&lds_a[(wr * 64 + r * 16 + l15) * BK + l4 * 8];
#pragma unroll
        for (int c = 0; c < 4; c++)
            bfr[c] = *(const bf16x8*)&lds_b[(wc * 64 + c * 16 + l15) * BK + l4 * 8];

#pragma unroll
        for (int r = 0; r < 4; r++)
#pragma unroll
            for (int c = 0; c < 4; c++)
                acc[r][c] = __builtin_amdgcn_mfma_f32_16x16x32_bf16(af[r], bfr[c], acc[r][c], 0, 0, 0);

        __syncthreads();  // protect LDS reuse
    }

    // epilogue: D mapping col = lane&15, row = (lane>>4)*4 + j
#pragma unroll
    for (int c = 0; c < 4; c++) {
        const long n = n0 + wc * 64 + c * 16 + l15;
        const float bv = bias[n];
#pragma unroll
        for (int r = 0; r < 4; r++) {
            const long m = m0 + wr * 64 + r * 16 + l4 * 4;
            float* Cp = C + m * (long)N + n;
#pragma unroll
            for (int j = 0; j < 4; j++)
                Cp[(long)j * N] = acc[r][c][j] + bv;
        }
    }
}

// Emergency fallback if ws is too small for bf16 copies: fp32 LDS-tiled GEMM.
__global__ __launch_bounds__(256) void gemm_f32_fallback(const float* __restrict__ A,
                                                         const float* __restrict__ Bw,
                                                         const float* __restrict__ bias,
                                                         float* __restrict__ C,
                                                         int M, int N, int K) {
    __shared__ float sa[64][33];
    __shared__ float sb[64][33];
    const int tid = threadIdx.x;
    const int tx = tid & 15, ty = tid >> 4;
    const int nTn = N / 64;
    const long m0 = (long)(blockIdx.x / nTn) * 64;
    const long n0 = (long)(blockIdx.x % nTn) * 64;
    float acc[4][4] = {};
    for (int k0 = 0; k0 < K; k0 += 32) {
#pragma unroll
        for (int i = 0; i < 8; i++) {
            int e = i * 256 + tid;
            int r = e >> 5, c = e & 31;
            sa[r][c] = A[(m0 + r) * (long)K + k0 + c];
            sb[r][c] = Bw[(n0 + r) * (long)K + k0 + c];
        }
        __syncthreads();
#pragma unroll 4
        for (int kk = 0; kk < 32; kk++) {
            float av[4], bv[4];
#pragma unroll
            for (int i = 0; i < 4; i++) av[i] = sa[ty * 4 + i][kk];
#pragma unroll
            for (int j = 0; j < 4; j++) bv[j] = sb[tx * 4 + j][kk];
#pragma unroll
            for (int i = 0; i < 4; i++)
#pragma unroll
                for (int j = 0; j < 4; j++) acc[i][j] += av[i] * bv[j];
        }
        __syncthreads();
    }
#pragma unroll
    for (int i = 0; i < 4; i++)
#pragma unroll
        for (int j = 0; j < 4; j++) {
            long m = m0 + ty * 4 + i, n = n0 + tx * 4 + j;
            C[m * (long)N + n] = acc[i][j] + bias[n];
        }
}

extern "C" void kernel_launch(void* const* d_in, const int* in_sizes, int n_in,
                              void* d_out, int out_size, void* d_ws, size_t ws_size,
                              hipStream_t stream) {
    const float* x    = (const float*)d_in[0];
    const float* w    = (const float*)d_in[1];
    const float* bias = (const float*)d_in[2];
    float* out = (float*)d_out;

    const long Nn = in_sizes[2];             // OUT = 4096
    const long Kk = (long)in_sizes[1] / Nn;  // IN  = 16384
    const long Mm = (long)in_sizes[0] / Kk;  // B*S = 8192

    const size_t need = (size_t)(Mm * Kk + Nn * Kk) * sizeof(unsigned short);
    if (ws_size >= need) {
        unsigned short* aB = (unsigned short*)d_ws;
        unsigned short* bB = aB + Mm * Kk;
        cvt_f32_bf16<<<2048, 256, 0, stream>>>(x, aB, Mm * Kk);
        cvt_f32_bf16<<<2048, 256, 0, stream>>>(w, bB, Nn * Kk);
        const int grid = (int)((Mm / BM) * (Nn / BN));
        gemm_bt_bias<<<grid, 256, 0, stream>>>(aB, bB, bias, out,
                                               (int)Mm, (int)Nn, (int)Kk);
    } else {
        const int grid = (int)((Mm / 64) * (Nn / 64));
        gemm_f32_fallback<<<grid, 256, 0, stream>>>(x, w, bias, out,
                                                    (int)Mm, (int)Nn, (int)Kk);
    }
}

// Round 2
// 1154.351 us; speedup vs baseline: 1.7375x; 1.7375x over previous
//
#include <hip/hip_runtime.h>
#include <hip/hip_bf16.h>
#include <stdint.h>

typedef float  f32x4  __attribute__((ext_vector_type(4)));
typedef __bf16 bf16x8 __attribute__((ext_vector_type(8)));
typedef unsigned short u16x8 __attribute__((ext_vector_type(8)));

__device__ __forceinline__ unsigned short f2bf_rne(float f) {
    uint32_t x = __float_as_uint(f);
    uint32_t r = x + 0x7FFFu + ((x >> 16) & 1u);
    return (unsigned short)(r >> 16);
}

__global__ __launch_bounds__(256) void cvt_f32_bf16(const float* __restrict__ src,
                                                    unsigned short* __restrict__ dst,
                                                    long n) {
    long i0 = ((long)blockIdx.x * blockDim.x + threadIdx.x) * 8;
    long stride = (long)gridDim.x * blockDim.x * 8;
    for (long j = i0; j + 8 <= n; j += stride) {
        float4 v0 = *(const float4*)(src + j);
        float4 v1 = *(const float4*)(src + j + 4);
        u16x8 o;
        o[0] = f2bf_rne(v0.x); o[1] = f2bf_rne(v0.y);
        o[2] = f2bf_rne(v0.z); o[3] = f2bf_rne(v0.w);
        o[4] = f2bf_rne(v1.x); o[5] = f2bf_rne(v1.y);
        o[6] = f2bf_rne(v1.z); o[7] = f2bf_rne(v1.w);
        *(u16x8*)(dst + j) = o;
    }
}

#define GLL(SRC, DST) __builtin_amdgcn_global_load_lds(                      \
    (const __attribute__((address_space(1))) void*)(SRC),                    \
    (__attribute__((address_space(3))) void*)(DST), 16, 0, 0)
#define BARRIER() asm volatile("s_barrier" ::: "memory")

// 256x256 tile, BK=64, 8 waves (2M x 4N), double-buffered 128 KiB LDS,
// 4-phase-per-K-tile schedule with counted vmcnt (never 0 in steady state),
// XOR bank swizzle (linear LDS dest + inverse-swizzled global src + swizzled read).
__global__ __launch_bounds__(512, 2) void gemm256_8p(
    const unsigned short* __restrict__ A, const unsigned short* __restrict__ B,
    const float* __restrict__ bias, float* __restrict__ C,
    int M, int N, int K) {
    __shared__ __align__(16) char lds[131072];
    const int tid  = threadIdx.x;
    const int lane = tid & 63;
    const int wave = tid >> 6;
    const int wr  = wave >> 2;   // 0..1
    const int wc  = wave & 3;    // 0..3
    const int l15 = lane & 15;
    const int l4  = lane >> 4;

    // bijective XCD swizzle
    int bid = blockIdx.x, nwg = gridDim.x;
    int qq = nwg >> 3, rr = nwg & 7, xc = bid & 7, oo = bid >> 3;
    int wg = (xc < rr ? xc * (qq + 1) : rr * (qq + 1) + (xc - rr) * qq) + oo;
    const int nTn = N >> 8;
    const long m0 = (long)(wg / nTn) << 8;
    const long n0 = (long)(wg % nTn) << 8;

    const int colSw = ((tid & 7) ^ ((tid >> 3) & 7)) << 3;  // inverse-swizzled k-block
    const int aRow  = tid >> 3;         // 0..63
    const int bWcLo = tid >> 8;         // 0..1
    const int bR    = (tid >> 3) & 31;  // 0..31
    const long Kl = K;

    // stage unit layouts (16 KiB each):
    // A buf: [unit u][wr-half][64][64] at (buf<<16) + (u<<14) + (wrpart<<13)
    // B buf: [unit u][wc][32][64]      at (buf<<16) + 32768 + (u<<14) + (wc<<12)
    auto STAGE_A = [&](int buf, int u, int t) {
        char* dst = lds + (buf << 16) + (u << 14) + tid * 16;
        long col = (long)t * 64 + colSw;
#pragma unroll
        for (int i = 0; i < 2; ++i) {
            const unsigned short* src = A + (m0 + i * 128 + u * 64 + aRow) * Kl + col;
            GLL(src, dst + i * 8192);
        }
    };
    auto STAGE_B = [&](int buf, int u, int t) {
        char* dst = lds + (buf << 16) + 32768 + (u << 14) + tid * 16;
        long col = (long)t * 64 + colSw;
#pragma unroll
        for (int i = 0; i < 2; ++i) {
            const unsigned short* src = B + (n0 + (i * 2 + bWcLo) * 64 + u * 32 + bR) * Kl + col;
            GLL(src, dst + i * 8192);
        }
    };
    auto LDA = [&](int buf, int mh, int m, int kk) -> bf16x8 {
        int off = (((m * 16 + l15) * 64 + kk * 32 + l4 * 8) * 2) ^ ((l15 & 7) << 4);
        return *(const bf16x8*)(lds + (buf << 16) + (mh << 14) + (wr << 13) + off);
    };
    auto LDB = [&](int buf, int nh, int n, int kk) -> bf16x8 {
        int off = (((n * 16 + l15) * 64 + kk * 32 + l4 * 8) * 2) ^ ((l15 & 7) << 4);
        return *(const bf16x8*)(lds + (buf << 16) + 32768 + (nh << 14) + (wc << 12) + off);
    };

    f32x4 acc[8][4] = {};
    bf16x8 af[4][2], bq[2][2];
    const int NT = K >> 6;

    // prologue: tile0 (4 units) -> buf0; vmcnt(4); tile1 minus s3 -> buf1; vmcnt(6)
    STAGE_A(0, 0, 0); STAGE_B(0, 0, 0); STAGE_B(0, 1, 0); STAGE_A(0, 1, 0);
    asm volatile("s_waitcnt vmcnt(4)" ::: "memory");
    STAGE_A(1, 0, 1); STAGE_B(1, 1, 1); STAGE_A(1, 1, 1);
    asm volatile("s_waitcnt vmcnt(6)" ::: "memory");
    BARRIER();

    for (int t = 0; t < NT; ++t) {
        const int cur = t & 1, nxt = cur ^ 1;
        // ---------- phase 1: quadrant (mh=0, nh=0) ----------
#pragma unroll
        for (int m = 0; m < 4; ++m) { af[m][0] = LDA(cur, 0, m, 0); af[m][1] = LDA(cur, 0, m, 1); }
#pragma unroll
        for (int n = 0; n < 2; ++n) { bq[n][0] = LDB(cur, 0, n, 0); bq[n][1] = LDB(cur, 0, n, 1); }
        if (t + 1 < NT) STAGE_B(nxt, 0, t + 1);   // s3 of tile t+1
        BARRIER();
        asm volatile("s_waitcnt lgkmcnt(0)" ::: "memory");
        __builtin_amdgcn_sched_barrier(0);
        __builtin_amdgcn_s_setprio(1);
#pragma unroll
        for (int kk = 0; kk < 2; ++kk)
#pragma unroll
            for (int m = 0; m < 4; ++m)
#pragma unroll
                for (int n = 0; n < 2; ++n)
                    acc[m][n] = __builtin_amdgcn_mfma_f32_16x16x32_bf16(af[m][kk], bq[n][kk], acc[m][n], 0, 0, 0);
        __builtin_amdgcn_s_setprio(0);
        BARRIER();
        // ---------- phase 2: quadrant (mh=0, nh=1) ----------
#pragma unroll
        for (int n = 0; n < 2; ++n) { bq[n][0] = LDB(cur, 1, n, 0); bq[n][1] = LDB(cur, 1, n, 1); }
        if (t + 2 < NT) STAGE_A(cur, 0, t + 2);   // s1 of tile t+2
        BARRIER();
        asm volatile("s_waitcnt lgkmcnt(0)" ::: "memory");
        __builtin_amdgcn_sched_barrier(0);
        __builtin_amdgcn_s_setprio(1);
#pragma unroll
        for (int kk = 0; kk < 2; ++kk)
#pragma unroll
            for (int m = 0; m < 4; ++m)
#pragma unroll
                for (int n = 0; n < 2; ++n)
                    acc[m][2 + n] = __builtin_amdgcn_mfma_f32_16x16x32_bf16(af[m][kk], bq[n][kk], acc[m][2 + n], 0, 0, 0);
        __builtin_amdgcn_s_setprio(0);
        BARRIER();
        // ---------- phase 3: quadrant (mh=1, nh=1) ----------
#pragma unroll
        for (int m = 0; m < 4; ++m) { af[m][0] = LDA(cur, 1, m, 0); af[m][1] = LDA(cur, 1, m, 1); }
        if (t + 2 < NT) STAGE_B(cur, 1, t + 2);   // s4 of tile t+2
        BARRIER();
        asm volatile("s_waitcnt lgkmcnt(0)" ::: "memory");
        __builtin_amdgcn_sched_barrier(0);
        __builtin_amdgcn_s_setprio(1);
#pragma unroll
        for (int kk = 0; kk < 2; ++kk)
#pragma unroll
            for (int m = 0; m < 4; ++m)
#pragma unroll
                for (int n = 0; n < 2; ++n)
                    acc[4 + m][2 + n] = __builtin_amdgcn_mfma_f32_16x16x32_bf16(af[m][kk], bq[n][kk], acc[4 + m][2 + n], 0, 0, 0);
        __builtin_amdgcn_s_setprio(0);
        BARRIER();
        // ---------- phase 4: quadrant (mh=1, nh=0) ----------
#pragma unroll
        for (int n = 0; n < 2; ++n) { bq[n][0] = LDB(cur, 0, n, 0); bq[n][1] = LDB(cur, 0, n, 1); }
        if (t + 2 < NT) STAGE_A(cur, 1, t + 2);   // s2 of tile t+2
        if (t == NT - 2) { asm volatile("s_waitcnt vmcnt(0)" ::: "memory"); }
        else             { asm volatile("s_waitcnt vmcnt(6)" ::: "memory"); }
        BARRIER();
        asm volatile("s_waitcnt lgkmcnt(0)" ::: "memory");
        __builtin_amdgcn_sched_barrier(0);
        __builtin_amdgcn_s_setprio(1);
#pragma unroll
        for (int kk = 0; kk < 2; ++kk)
#pragma unroll
            for (int m = 0; m < 4; ++m)
#pragma unroll
                for (int n = 0; n < 2; ++n)
                    acc[4 + m][n] = __builtin_amdgcn_mfma_f32_16x16x32_bf16(af[m][kk], bq[n][kk], acc[4 + m][n], 0, 0, 0);
        __builtin_amdgcn_s_setprio(0);
        BARRIER();
    }

    // epilogue: D mapping col = l15, row = l4*4 + j within each 16x16 fragment
#pragma unroll
    for (int nf = 0; nf < 4; ++nf) {
        const long col = n0 + wc * 64 + nf * 16 + l15;
        const float bv = bias[col];
#pragma unroll
        for (int mf = 0; mf < 8; ++mf) {
            float* Cp = C + (m0 + wr * 128 + mf * 16 + l4 * 4) * (long)N + col;
#pragma unroll
            for (int j = 0; j < 4; ++j)
                Cp[(long)j * N] = acc[mf][nf][j] + bv;
        }
    }
}

// fallback: m97-structure 128x128 (verified round 1)
__global__ __launch_bounds__(256) void gemm_bt_bias(const unsigned short* __restrict__ A,
                                                    const unsigned short* __restrict__ B,
                                                    const float* __restrict__ bias,
                                                    float* __restrict__ C,
                                                    int M, int N, int K) {
    __shared__ unsigned short lds_a[128 * 32];
    __shared__ unsigned short lds_b[128 * 32];
    const int tid  = threadIdx.x;
    const int lane = tid & 63;
    const int wave = tid >> 6;
    const int wrr = wave >> 1, wcc = wave & 1;
    const int l15 = lane & 15, l4 = lane >> 4;
    const int nTilesN = N / 128;
    const long m0 = (long)(blockIdx.x / nTilesN) * 128;
    const long n0 = (long)(blockIdx.x % nTilesN) * 128;
    f32x4 acc[4][4] = {};
    const unsigned short* aSrc = A + (m0 + (tid >> 2)) * (long)K + ((tid & 3) * 8);
    const unsigned short* bSrc = B + (n0 + (tid >> 2)) * (long)K + ((tid & 3) * 8);
    char* aDst = (char*)lds_a + tid * 16;
    char* bDst = (char*)lds_b + tid * 16;
    for (int k0 = 0; k0 < K; k0 += 32) {
#pragma unroll
        for (int i = 0; i < 2; i++) {
            GLL(aSrc + (long)i * 64 * K + k0, aDst + i * 4096);
            GLL(bSrc + (long)i * 64 * K + k0, bDst + i * 4096);
        }
        __syncthreads();
        bf16x8 afr[4], bfr[4];
#pragma unroll
        for (int r = 0; r < 4; r++)
            afr[r] = *(const bf16x8*)&lds_a[(wrr * 64 + r * 16 + l15) * 32 + l4 * 8];
#pragma unroll
        for (int c = 0; c < 4; c++)
            bfr[c] = *(const bf16x8*)&lds_b[(wcc * 64 + c * 16 + l15) * 32 + l4 * 8];
#pragma unroll
        for (int r = 0; r < 4; r++)
#pragma unroll
            for (int c = 0; c < 4; c++)
                acc[r][c] = __builtin_amdgcn_mfma_f32_16x16x32_bf16(afr[r], bfr[c], acc[r][c], 0, 0, 0);
        __syncthreads();
    }
#pragma unroll
    for (int c = 0; c < 4; c++) {
        const long n = n0 + wcc * 64 + c * 16 + l15;
        const float bv = bias[n];
#pragma unroll
        for (int r = 0; r < 4; r++) {
            const long m = m0 + wrr * 64 + r * 16 + l4 * 4;
            float* Cp = C + m * (long)N + n;
#pragma unroll
            for (int j = 0; j < 4; j++)
                Cp[(long)j * N] = acc[r][c][j] + bv;
        }
    }
}

extern "C" void kernel_launch(void* const* d_in, const int* in_sizes, int n_in,
                              void* d_out, int out_size, void* d_ws, size_t ws_size,
                              hipStream_t stream) {
    const float* x    = (const float*)d_in[0];
    const float* w    = (const float*)d_in[1];
    const float* bias = (const float*)d_in[2];
    float* out = (float*)d_out;

    const long Nn = in_sizes[2];             // OUT = 4096
    const long Kk = (long)in_sizes[1] / Nn;  // IN  = 16384
    const long Mm = (long)in_sizes[0] / Kk;  // B*S = 8192

    unsigned short* aB = (unsigned short*)d_ws;
    unsigned short* bB = aB + Mm * Kk;
    cvt_f32_bf16<<<2048, 256, 0, stream>>>(x, aB, Mm * Kk);
    cvt_f32_bf16<<<2048, 256, 0, stream>>>(w, bB, Nn * Kk);

    if ((Mm & 255) == 0 && (Nn & 255) == 0 && (Kk & 63) == 0 && Kk >= 192) {
        const int grid = (int)((Mm >> 8) * (Nn >> 8));
        gemm256_8p<<<grid, 512, 0, stream>>>(aB, bB, bias, out, (int)Mm, (int)Nn, (int)Kk);
    } else {
        const int grid = (int)((Mm / 128) * (Nn / 128));
        gemm_bt_bias<<<grid, 256, 0, stream>>>(aB, bB, bias, out, (int)Mm, (int)Nn, (int)Kk);
    }
}